// Round 4
// baseline (254.718 us; speedup 1.0000x reference)
//
#include <hip/hip_runtime.h>

// Cost volume: out[b,d,h,w] = (w>=d) ? (1/32) * sum_c L[b,c,h,w]*R[b,c,h,w-d] : 0
// B=4, C=32, H=256, W=512, D=64, fp32 (no fp32-input MFMA on CDNA4).
//
// v4 resubmit (round-3 bench died with "container failed twice" = infra, no
// counters; kernel audited for barrier-divergence / vmcnt / WAR hazards --
// none found; staging mechanics identical to v2/v3 which passed).
//
// Theory: v1/v2/v3 all pin at VALU 22-25% regardless of occupancy or chain
// structure. Staging is HBM-supply-bound AND bursty: __syncthreads() drains
// vmcnt(0) every chunk (read BW observed only 0.74 TB/s). Fix = counted
// vmcnt ring (guide T3/T4): 4 LDS slots (CCH=4), 3 chunks issued ahead, raw
// s_barrier + s_waitcnt vmcnt(4) -- loads stay in flight across barriers,
// HBM sees continuous queue pressure.
//
// Per-iter protocol (8 chunks):
//   s_waitcnt vmcnt(4)   ; chunk t's own loads complete, 2 chunks ahead stay
//   s_barrier            ; all waves' chunk-t loads complete; buffer (t-1)&3
//                        ; no longer read by anyone
//   stage((t+3)&3, t+3)  ; fire-and-forget into the just-freed buffer
//   compute(t)           ; pure LDS + FMA

constexpr int Bn = 4, Cn = 32, Hn = 256, Wn = 512, Dn = 64;
constexpr int CCH = 4;               // channels per chunk
constexpr int NCHUNK = Cn / CCH;     // 8
constexpr int NBUF = 4;              // ring depth (3 ahead)
constexpr int WT = 4, DT = 16;
constexpr int PAD = 64;              // zero pad -> automatic w<d masking
constexpr int STRIDE = PAD + Wn;     // 576 floats per R channel row
constexpr int HW = Hn * Wn;          // 131072
constexpr int RBUF = CCH * STRIDE;   // 2304 floats per ring slot
constexpr int LBUF = CCH * Wn;       // 2048 floats per ring slot

__global__ __launch_bounds__(512, 4)
void cost_volume_kernel(const float* __restrict__ left,
                        const float* __restrict__ right,
                        float* __restrict__ out)
{
    __shared__ __align__(16) float Rs[NBUF * RBUF];   // 36,864 B
    __shared__ __align__(16) float Ls[NBUF * LBUF];   // 32,768 B  (69.6 KB total)

    const int tid = threadIdx.x;
    const int bh  = blockIdx.x;
    const int b   = bh >> 8;          // H = 256
    const int h   = bh & (Hn - 1);

    const float* Lrow = left  + (b * Cn * Hn + h) * Wn;   // channel stride = HW
    const float* Rrow = right + (b * Cn * Hn + h) * Wn;

    // --- zero left pads of ALL ring slots once (staging never writes pads):
    // 4 bufs x 4 ch x 64 floats = 256 float4, threads 0..255
    if (tid < NBUF * CCH * (PAD / 4)) {
        const int buf = tid >> 6;               // 64 float4 of pad per buffer
        const int c   = (tid >> 4) & (CCH - 1);
        const int wq  = (tid & 15) << 2;
        *reinterpret_cast<float4*>(&Rs[buf * RBUF + c * STRIDE + wq]) =
            make_float4(0.f, 0.f, 0.f, 0.f);
    }

    // --- staging: one chunk = 4 ch x 512 floats of R and of L = 512 float4
    // each; 512 threads -> exactly 1 global_load_lds for R + 1 for L per
    // thread. LDS dest = wave-uniform base + lane*16 (waves never straddle
    // channel rows: 128 float4 per row, wave covers 64).
    const int sc = tid >> 7;                    // staging channel 0..3
    const int sw = (tid & 127) << 2;            // staging w offset
    auto stage = [&](int sel, int chunk) {
        const int gc = chunk * CCH + sc;
        __builtin_amdgcn_global_load_lds(
            (const __attribute__((address_space(1))) void*)(Rrow + gc * HW + sw),
            (__attribute__((address_space(3))) void*)(&Rs[sel * RBUF + sc * STRIDE + PAD + sw]),
            16, 0, 0);
        __builtin_amdgcn_global_load_lds(
            (const __attribute__((address_space(1))) void*)(Lrow + gc * HW + sw),
            (__attribute__((address_space(3))) void*)(&Ls[sel * LBUF + sc * Wn + sw]),
            16, 0, 0);
    };

    // pads visible to all waves before anyone computes; no loads in flight yet
    __syncthreads();

    // prologue: 3 chunks in flight
    stage(0, 0);
    stage(1, 1);
    stage(2, 2);

    // --- thread tile: tw in [0,128) covers w, td in [0,4) covers d
    const int tw = tid & 127;
    const int td = tid >> 7;
    const int w0 = tw << 2;                 // WT=4
    const int d0 = td << 4;                 // DT=16
    const int rbase = PAD + w0 - d0 - 16;   // >= 0, multiple of 4

    float acc[DT][WT];
    #pragma unroll
    for (int j = 0; j < DT; ++j)
        #pragma unroll
        for (int i = 0; i < WT; ++i)
            acc[j][i] = 0.f;

    #pragma unroll
    for (int t = 0; t < NCHUNK; ++t) {
        // Counted wait: chunk t's 2 loads (this wave) complete; up to 2
        // chunks (4 loads) stay in flight across the barrier. t folds to a
        // compile-time constant under full unroll.
        if (t < 6)       asm volatile("s_waitcnt vmcnt(4)" ::: "memory");
        else if (t == 6) asm volatile("s_waitcnt vmcnt(2)" ::: "memory");
        else             asm volatile("s_waitcnt vmcnt(0)" ::: "memory");
        __builtin_amdgcn_sched_barrier(0);
        __builtin_amdgcn_s_barrier();
        __builtin_amdgcn_sched_barrier(0);

        if (t + 3 < NCHUNK)
            stage((t + 3) & (NBUF - 1), t + 3);   // into buffer freed above

        const float* Rb = &Rs[(t & (NBUF - 1)) * RBUF];
        const float* Lb = &Ls[(t & (NBUF - 1)) * LBUF];

        #pragma unroll 2
        for (int c = 0; c < CCH; ++c) {
            const float4 Lv =
                *reinterpret_cast<const float4*>(&Lb[c * Wn + w0]);

            const float* rp = &Rb[c * STRIDE + rbase];
            float r[20];                    // window R[w0-d0-16 .. w0-d0+3]
            #pragma unroll
            for (int q = 0; q < 5; ++q)
                *reinterpret_cast<float4*>(&r[q * 4]) =
                    *reinterpret_cast<const float4*>(&rp[q * 4]);

            // acc[j][i] += L[c][w0+i] * R[c][w0+i-(d0+j)] -> r[16+i-j] in [1,19]
            #pragma unroll
            for (int j = 0; j < DT; ++j) {
                acc[j][0] = fmaf(Lv.x, r[16 - j], acc[j][0]);
                acc[j][1] = fmaf(Lv.y, r[17 - j], acc[j][1]);
                acc[j][2] = fmaf(Lv.z, r[18 - j], acc[j][2]);
                acc[j][3] = fmaf(Lv.w, r[19 - j], acc[j][3]);
            }
        }
    }

    // --- epilogue: out[b][d0+j][h][w0..w0+3], coalesced dwordx4 per j
    constexpr float inv = 1.0f / 32.0f;
    float* op = out + ((b * Dn + d0) * Hn + h) * Wn + w0;
    #pragma unroll
    for (int j = 0; j < DT; ++j) {
        const float4 v = make_float4(acc[j][0] * inv, acc[j][1] * inv,
                                     acc[j][2] * inv, acc[j][3] * inv);
        *reinterpret_cast<float4*>(&op[j * HW]) = v;
    }
}

extern "C" void kernel_launch(void* const* d_in, const int* in_sizes, int n_in,
                              void* d_out, int out_size, void* d_ws, size_t ws_size,
                              hipStream_t stream) {
    const float* left  = (const float*)d_in[0];
    const float* right = (const float*)d_in[1];
    float* out = (float*)d_out;
    cost_volume_kernel<<<dim3(Bn * Hn), dim3(512), 0, stream>>>(left, right, out);
}